// Round 6
// baseline (345.062 us; speedup 1.0000x reference)
//
#include <hip/hip_runtime.h>

#define TT 365
#define NB 16
#define NTH 1024   // 16 waves: 0-7 = L2 (E) group, 8-15 = L1 (D) group
#define XLEN (NB * TT * 3)

typedef _Float16 halfx8 __attribute__((ext_vector_type(8)));
typedef float floatx4 __attribute__((ext_vector_type(4)));
typedef float floatx2 __attribute__((ext_vector_type(2)));

#define MMH(A, B, C) __builtin_amdgcn_mfma_f32_16x16x32_f16((A), (B), (C), 0, 0, 0)

// Gate rows PRE-SCALED: sigmoid rows by -log2e, g rows by -2log2e.
#define SGP -2.8853900817779268f
#define SGN  2.8853900817779268f
#define SS_  -1.4426950408889634f

static __device__ __forceinline__ float rcpf(float x) { return __builtin_amdgcn_rcpf(x); }
static __device__ __forceinline__ float ex2(float x)  { return __builtin_amdgcn_exp2f(x); }

// one-way producer/consumer sync: monotonic LDS counters, 1 add per wave per step
static __device__ __forceinline__ void publish(unsigned* c, int lane) {
  __threadfence_block();   // drain LDS writes before the release add
  if (lane == 0)
    __hip_atomic_fetch_add(c, 1u, __ATOMIC_RELEASE, __HIP_MEMORY_SCOPE_WORKGROUP);
}
static __device__ __forceinline__ void spin_ge(unsigned* c, unsigned tgt) {
  while (__hip_atomic_load(c, __ATOMIC_ACQUIRE, __HIP_MEMORY_SCOPE_WORKGROUP) < tgt) { }
}

#define LOADFRAG(SRC, SCALE, HI)                                               \
  do {                                                                         \
    _Pragma("unroll")                                                          \
    for (int jj = 0; jj < 8; ++jj) {                                           \
      (HI)[jj] = (_Float16)((SCALE) * (SRC)[jj]);                              \
    }                                                                          \
  } while (0)

// Packed tail, combined-rcp cell update (1 rcp for f & i*g paths):
//   c' = [c*(1+ei)(1+eg) + SGP*(1-eg)*(1+ef)] / [(1+ef)(1+ei)(1+eg)]
//   h  = (1-ec) / [(1+eo)(1+ec)],  ec = 2^c'  (c kept in SG-scaled domain)
#define PTAIL_CORE(PA, PB, CS2, HOUT)                                          \
  const floatx2 one_ = {1.0f, 1.0f};                                           \
  const floatx2 ei_ = {ex2((PA)[0]), ex2((PB)[0])};                            \
  const floatx2 ef_ = {ex2((PA)[1]), ex2((PB)[1])};                            \
  const floatx2 eg_ = {ex2((PA)[2]), ex2((PB)[2])};                            \
  const floatx2 eo_ = {ex2((PA)[3]), ex2((PB)[3])};                            \
  const floatx2 sgn2_ = {SGN, SGN};                                            \
  const floatx2 sgp2_ = {SGP, SGP};                                            \
  const floatx2 fd_ = one_ + ef_;                                              \
  const floatx2 P1_ = (one_ + ei_) * (one_ + eg_);                             \
  const floatx2 Dp_ = P1_ * fd_;                                               \
  const floatx2 R_  = {rcpf(Dp_.x), rcpf(Dp_.y)};                              \
  const floatx2 T_  = (sgn2_ * eg_ + sgp2_) * fd_;                             \
  (CS2) = ((CS2) * P1_ + T_) * R_;                                             \
  (CS2).x = fminf((CS2).x, 60.0f);                                             \
  (CS2).y = fminf((CS2).y, 60.0f);                                             \
  const floatx2 ec_ = {ex2((CS2).x), ex2((CS2).y)};                            \
  const floatx2 P2_ = (one_ + eo_) * (one_ + ec_);                             \
  const floatx2 R2_ = {rcpf(P2_.x), rcpf(P2_.y)};                              \
  const floatx2 HOUT = (one_ - ec_) * R2_;

// pack both h (adjacent units) into one b32 LDS write
#define PTAIL(PA, PB, CS2, ZW32, WIDX)                                         \
  do {                                                                         \
    PTAIL_CORE(PA, PB, CS2, hv_)                                               \
    (ZW32)[WIDX] =                                                             \
        __builtin_bit_cast(unsigned, __builtin_amdgcn_cvt_pkrtz(hv_.x, hv_.y)); \
  } while (0)

__global__ __launch_bounds__(NTH)
__attribute__((amdgpu_waves_per_eu(4, 4)))
void lstm2_mfma17(
    const float* __restrict__ x,
    const float* __restrict__ w_ih0, const float* __restrict__ w_hh0,
    const float* __restrict__ b_ih0, const float* __restrict__ b_hh0,
    const float* __restrict__ w_ih1, const float* __restrict__ w_hh1,
    const float* __restrict__ b_ih1, const float* __restrict__ b_hh1,
    float* __restrict__ out)
{
  // h1 ring (4 deep) and h2 double-buffer, fp16 [kt][lane][8] layout per slot
  __shared__ __align__(16) unsigned short Zh1[4][1024];
  __shared__ __align__(16) unsigned short Zh2[2][1024];
  __shared__ __align__(16) float xh[TT * 16 * 4];   // x re-laid: [t][b][4]
  __shared__ unsigned cnt[16];                      // cnt[0]=d_arrive, cnt[8]=e_arrive

  const int tid  = threadIdx.x;
  const int lane = tid & 63;
  const int wv   = tid >> 6;
  const int n15  = lane & 15;
  const int quad = lane >> 4;
  const int bbase = blockIdx.x * NB;
  const float sA = ((n15 & 3) == 2) ? SGP : SS_;

  // stage x -> [t][b][4] layout (coalesced global reads, scattered LDS writes)
  {
    const float* xg = x + (size_t)bbase * (TT * 3);
    for (int i = tid; i < XLEN; i += NTH) {
      const int b = i / 1095;
      const int rem = i - b * 1095;
      const int t = rem / 3;
      const int c = rem - 3 * t;
      xh[(t * 16 + b) * 4 + c] = xg[i];
    }
    for (int i = tid; i < 4096; i += NTH) (&Zh1[0][0])[i] = 0;
    for (int i = tid; i < 2048; i += NTH) (&Zh2[0][0])[i] = 0;
    if (tid < 16) cnt[tid] = 0;
  }
  __syncthreads();   // the ONLY block-wide barrier; groups free-run after this

  if (wv < 8) {
    // ================= E group: layer-2 GEMM + combine2 =================
    const int w = wv;
    halfx8 a2[2][4];
    floatx4 b1v[2];
    #pragma unroll
    for (int tt = 0; tt < 2; ++tt) {
      const int arow = (n15 & 3) * 64 + 8 * w + 2 * (n15 >> 2) + tt;
      #pragma unroll
      for (int kt = 0; kt < 4; ++kt) {
        const int k0 = kt * 32 + quad * 8;
        const float* src = (k0 < 64) ? (w_ih1 + arow * 64 + k0)
                                     : (w_hh1 + arow * 64 + (k0 - 64));
        LOADFRAG(src, sA, a2[tt][kt]);
      }
      #pragma unroll
      for (int r = 0; r < 4; ++r) {
        const int crow = r * 64 + 8 * w + 2 * quad + tt;
        const float sC = (r == 2) ? SGP : SS_;
        b1v[tt][r] = sC * (b_ih1[crow] + b_hh1[crow]);
      }
    }
    const int j0 = 8 * w + 2 * quad;
    const int widx = (w >> 2) * 256 + (w & 3) * 64 + n15 * 4 + quad;  // within Zh2 slot
    floatx2 c2v = {0.f, 0.f};

    // E(t): needs all-E past t-1 (h2(t-1) complete) and D past t (h1(t) ready)
    #pragma unroll 4
    for (int t = 0; t < 364; ++t) {
      spin_ge(&cnt[8], 8u * (unsigned)t);
      spin_ge(&cnt[0], 8u * (unsigned)(t + 1));
      const halfx8* r1 = (const halfx8*)(&Zh1[t & 3][0]) + lane;
      const halfx8* r2 = (const halfx8*)(&Zh2[t & 1][0]) + lane;
      const halfx8 bh0 = r1[0], bh1 = r1[64];
      const halfx8 bh2 = r2[0], bh3 = r2[64];
      floatx4 e0 = b1v[0], e1 = b1v[1];
      e0 = MMH(a2[0][0], bh0, e0); e0 = MMH(a2[0][1], bh1, e0);
      e0 = MMH(a2[0][2], bh2, e0); e0 = MMH(a2[0][3], bh3, e0);
      e1 = MMH(a2[1][0], bh0, e1); e1 = MMH(a2[1][1], bh1, e1);
      e1 = MMH(a2[1][2], bh2, e1); e1 = MMH(a2[1][3], bh3, e1);
      unsigned* zw = (unsigned*)(&Zh2[(t + 1) & 1][0]);
      PTAIL(e0, e1, c2v, zw, widx);
      publish(&cnt[8], lane);
    }

    // peel t=364: gates2 -> h2(364) -> out (units j0, j0+1 adjacent)
    {
      spin_ge(&cnt[8], 8u * 364u);
      spin_ge(&cnt[0], 8u * 365u);
      const halfx8* r1 = (const halfx8*)(&Zh1[364 & 3][0]) + lane;
      const halfx8* r2 = (const halfx8*)(&Zh2[364 & 1][0]) + lane;
      const halfx8 bh0 = r1[0], bh1 = r1[64];
      const halfx8 bh2 = r2[0], bh3 = r2[64];
      floatx4 e0 = b1v[0], e1 = b1v[1];
      e0 = MMH(a2[0][0], bh0, e0); e0 = MMH(a2[0][1], bh1, e0);
      e0 = MMH(a2[0][2], bh2, e0); e0 = MMH(a2[0][3], bh3, e0);
      e1 = MMH(a2[1][0], bh0, e1); e1 = MMH(a2[1][1], bh1, e1);
      e1 = MMH(a2[1][2], bh2, e1); e1 = MMH(a2[1][3], bh3, e1);
      PTAIL_CORE(e0, e1, c2v, hv_)
      *(floatx2*)(out + (size_t)(bbase + n15) * 64 + j0) = hv_;
    }
  } else {
    // ================= D group: layer-1 GEMM + combine1 =================
    const int u = wv - 8;
    halfx8 a1[2][2];
    floatx4 wiX[2], wiY[2], wiZ[2], b0v[2];
    #pragma unroll
    for (int tt = 0; tt < 2; ++tt) {
      const int arow = (n15 & 3) * 64 + 8 * u + 2 * (n15 >> 2) + tt;
      #pragma unroll
      for (int kt = 0; kt < 2; ++kt) {
        const float* src = w_hh0 + arow * 64 + kt * 32 + quad * 8;
        LOADFRAG(src, sA, a1[tt][kt]);
      }
      #pragma unroll
      for (int r = 0; r < 4; ++r) {
        const int crow = r * 64 + 8 * u + 2 * quad + tt;
        const float sC = (r == 2) ? SGP : SS_;
        wiX[tt][r] = sC * w_ih0[crow * 3 + 0];
        wiY[tt][r] = sC * w_ih0[crow * 3 + 1];
        wiZ[tt][r] = sC * w_ih0[crow * 3 + 2];
        b0v[tt][r] = sC * (b_ih0[crow] + b_hh0[crow]);
      }
    }
    const int widx = (u >> 2) * 256 + (u & 3) * 64 + n15 * 4 + quad;  // within Zh1 slot
    floatx2 c1v = {0.f, 0.f};

    // prologue: h1(0) from x(0) only -> Zh1[0], then publish (no block barrier)
    {
      const floatx4 xv = *(const floatx4*)(xh + n15 * 4);
      const floatx4 s0 = {xv[0], xv[0], xv[0], xv[0]};
      const floatx4 s1 = {xv[1], xv[1], xv[1], xv[1]};
      const floatx4 s2 = {xv[2], xv[2], xv[2], xv[2]};
      floatx4 d0 = __builtin_elementwise_fma(wiX[0], s0,
                     __builtin_elementwise_fma(wiY[0], s1,
                       __builtin_elementwise_fma(wiZ[0], s2, b0v[0])));
      floatx4 d1 = __builtin_elementwise_fma(wiX[1], s0,
                     __builtin_elementwise_fma(wiY[1], s1,
                       __builtin_elementwise_fma(wiZ[1], s2, b0v[1])));
      PTAIL(d0, d1, c1v, (unsigned*)(&Zh1[0][0]), widx);   // c1v=0 -> f-term vanishes
      publish(&cnt[0], lane);
    }

    // D(t): needs all-D past t-1 (h1(t-1) complete); ring-full guard vs E (lag 4)
    #pragma unroll 4
    for (int t = 1; t < 365; ++t) {
      spin_ge(&cnt[0], 8u * (unsigned)t);
      if (t >= 4) spin_ge(&cnt[8], 8u * (unsigned)(t - 3));
      const halfx8* rp = (const halfx8*)(&Zh1[(t - 1) & 3][0]) + lane;
      const halfx8 bh0 = rp[0], bh1 = rp[64];
      const floatx4 xv = *(const floatx4*)(xh + t * 64 + n15 * 4);
      const floatx4 s0 = {xv[0], xv[0], xv[0], xv[0]};
      const floatx4 s1 = {xv[1], xv[1], xv[1], xv[1]};
      const floatx4 s2 = {xv[2], xv[2], xv[2], xv[2]};
      floatx4 d0 = __builtin_elementwise_fma(wiX[0], s0,
                     __builtin_elementwise_fma(wiY[0], s1,
                       __builtin_elementwise_fma(wiZ[0], s2, b0v[0])));
      floatx4 d1 = __builtin_elementwise_fma(wiX[1], s0,
                     __builtin_elementwise_fma(wiY[1], s1,
                       __builtin_elementwise_fma(wiZ[1], s2, b0v[1])));
      d0 = MMH(a1[0][0], bh0, d0); d0 = MMH(a1[0][1], bh1, d0);
      d1 = MMH(a1[1][0], bh0, d1); d1 = MMH(a1[1][1], bh1, d1);
      unsigned* zw = (unsigned*)(&Zh1[t & 3][0]);
      PTAIL(d0, d1, c1v, zw, widx);
      publish(&cnt[0], lane);
    }
  }
}

extern "C" void kernel_launch(void* const* d_in, const int* in_sizes, int n_in,
                              void* d_out, int out_size, void* d_ws, size_t ws_size,
                              hipStream_t stream) {
  const float* x     = (const float*)d_in[0];
  const float* w_ih0 = (const float*)d_in[1];
  const float* w_hh0 = (const float*)d_in[2];
  const float* b_ih0 = (const float*)d_in[3];
  const float* b_hh0 = (const float*)d_in[4];
  const float* w_ih1 = (const float*)d_in[5];
  const float* w_hh1 = (const float*)d_in[6];
  const float* b_ih1 = (const float*)d_in[7];
  const float* b_hh1 = (const float*)d_in[8];
  float* out = (float*)d_out;

  const int B = in_sizes[0] / (TT * 3);   // 4096
  const int grid = B / NB;                // 256 blocks -> 1 per CU

  lstm2_mfma17<<<dim3(grid), dim3(NTH), 0, stream>>>(
      x, w_ih0, w_hh0, b_ih0, b_hh0, w_ih1, w_hh1, b_ih1, b_hh1, out);
}

// Round 7
// 341.942 us; speedup vs baseline: 1.0091x; 1.0091x over previous
//
#include <hip/hip_runtime.h>

#define TT 365
#define NB 16
#define NTH 1024   // 16 waves: 0-7 = L2 (E) group, 8-15 = L1 (D) group
#define XLEN (NB * TT * 3)

typedef _Float16 halfx8 __attribute__((ext_vector_type(8)));
typedef float floatx4 __attribute__((ext_vector_type(4)));
typedef float floatx2 __attribute__((ext_vector_type(2)));

#define MMH(A, B, C) __builtin_amdgcn_mfma_f32_16x16x32_f16((A), (B), (C), 0, 0, 0)

// Gate rows PRE-SCALED: sigmoid rows by -log2e, g rows by -2log2e.
#define SGP -2.8853900817779268f
#define SGN  2.8853900817779268f
#define SS_  -1.4426950408889634f

static __device__ __forceinline__ float rcpf(float x) { return __builtin_amdgcn_rcpf(x); }
static __device__ __forceinline__ float ex2(float x)  { return __builtin_amdgcn_exp2f(x); }

// one-way producer/consumer sync: monotonic LDS counters.
// publish: release RMW orders the wave's prior ds_writes (lane0 program order
// contains the wave-wide ds_write) -> no explicit threadfence needed.
static __device__ __forceinline__ void publish(unsigned* c, int lane) {
  if (lane == 0)
    __hip_atomic_fetch_add(c, 1u, __ATOMIC_RELEASE, __HIP_MEMORY_SCOPE_WORKGROUP);
}
// fast-path single load; sleep-throttled retry (no tight spin stealing issue)
static __device__ __forceinline__ void spin_ge(unsigned* c, unsigned tgt) {
  if (__hip_atomic_load(c, __ATOMIC_ACQUIRE, __HIP_MEMORY_SCOPE_WORKGROUP) >= tgt)
    return;
  do {
    __builtin_amdgcn_s_sleep(1);
  } while (__hip_atomic_load(c, __ATOMIC_ACQUIRE, __HIP_MEMORY_SCOPE_WORKGROUP) < tgt);
}

#define LOADFRAG(SRC, SCALE, HI)                                               \
  do {                                                                         \
    _Pragma("unroll")                                                          \
    for (int jj = 0; jj < 8; ++jj) {                                           \
      (HI)[jj] = (_Float16)((SCALE) * (SRC)[jj]);                              \
    }                                                                          \
  } while (0)

// Packed tail, combined-rcp cell update (1 rcp for f & i*g paths):
//   c' = [c*(1+ei)(1+eg) + SGP*(1-eg)*(1+ef)] / [(1+ef)(1+ei)(1+eg)]
//   h  = (1-ec) / [(1+eo)(1+ec)],  ec = 2^c'  (c kept in SG-scaled domain)
#define PTAIL_CORE(PA, PB, CS2, HOUT)                                          \
  const floatx2 one_ = {1.0f, 1.0f};                                           \
  const floatx2 ei_ = {ex2((PA)[0]), ex2((PB)[0])};                            \
  const floatx2 ef_ = {ex2((PA)[1]), ex2((PB)[1])};                            \
  const floatx2 eg_ = {ex2((PA)[2]), ex2((PB)[2])};                            \
  const floatx2 eo_ = {ex2((PA)[3]), ex2((PB)[3])};                            \
  const floatx2 sgn2_ = {SGN, SGN};                                            \
  const floatx2 sgp2_ = {SGP, SGP};                                            \
  const floatx2 fd_ = one_ + ef_;                                              \
  const floatx2 P1_ = (one_ + ei_) * (one_ + eg_);                             \
  const floatx2 Dp_ = P1_ * fd_;                                               \
  const floatx2 R_  = {rcpf(Dp_.x), rcpf(Dp_.y)};                              \
  const floatx2 T_  = (sgn2_ * eg_ + sgp2_) * fd_;                             \
  (CS2) = ((CS2) * P1_ + T_) * R_;                                             \
  (CS2).x = fminf((CS2).x, 60.0f);                                             \
  (CS2).y = fminf((CS2).y, 60.0f);                                             \
  const floatx2 ec_ = {ex2((CS2).x), ex2((CS2).y)};                            \
  const floatx2 P2_ = (one_ + eo_) * (one_ + ec_);                             \
  const floatx2 R2_ = {rcpf(P2_.x), rcpf(P2_.y)};                              \
  const floatx2 HOUT = (one_ - ec_) * R2_;

// pack both h (adjacent units) into one b32 LDS write
#define PTAIL(PA, PB, CS2, ZW32, WIDX)                                         \
  do {                                                                         \
    PTAIL_CORE(PA, PB, CS2, hv_)                                               \
    (ZW32)[WIDX] =                                                             \
        __builtin_bit_cast(unsigned, __builtin_amdgcn_cvt_pkrtz(hv_.x, hv_.y)); \
  } while (0)

__global__ __launch_bounds__(NTH)
__attribute__((amdgpu_waves_per_eu(4, 4)))
void lstm2_mfma18(
    const float* __restrict__ x,
    const float* __restrict__ w_ih0, const float* __restrict__ w_hh0,
    const float* __restrict__ b_ih0, const float* __restrict__ b_hh0,
    const float* __restrict__ w_ih1, const float* __restrict__ w_hh1,
    const float* __restrict__ b_ih1, const float* __restrict__ b_hh1,
    float* __restrict__ out)
{
  // h1 ring (4 deep) and h2 double-buffer, fp16 [kt][lane][8] layout per slot
  __shared__ __align__(16) unsigned short Zh1[4][1024];
  __shared__ __align__(16) unsigned short Zh2[2][1024];
  __shared__ __align__(16) float xh[TT * 16 * 4];   // x re-laid: [t][b][4]
  __shared__ unsigned cnt[16];                      // cnt[0]=d_arrive, cnt[8]=e_arrive

  const int tid  = threadIdx.x;
  const int lane = tid & 63;
  const int wv   = tid >> 6;
  const int n15  = lane & 15;
  const int quad = lane >> 4;
  const int bbase = blockIdx.x * NB;
  const float sA = ((n15 & 3) == 2) ? SGP : SS_;

  // stage x -> [t][b][4] layout (coalesced global reads, scattered LDS writes)
  {
    const float* xg = x + (size_t)bbase * (TT * 3);
    for (int i = tid; i < XLEN; i += NTH) {
      const int b = i / 1095;
      const int rem = i - b * 1095;
      const int t = rem / 3;
      const int c = rem - 3 * t;
      xh[(t * 16 + b) * 4 + c] = xg[i];
    }
    for (int i = tid; i < 4096; i += NTH) (&Zh1[0][0])[i] = 0;
    for (int i = tid; i < 2048; i += NTH) (&Zh2[0][0])[i] = 0;
    if (tid < 16) cnt[tid] = 0;
  }
  __syncthreads();   // the ONLY block-wide barrier; groups free-run after this

  if (wv < 8) {
    // ================= E group: layer-2 GEMM + combine2 =================
    const int w = wv;
    halfx8 a2[2][4];
    floatx4 b1v[2];
    #pragma unroll
    for (int tt = 0; tt < 2; ++tt) {
      const int arow = (n15 & 3) * 64 + 8 * w + 2 * (n15 >> 2) + tt;
      #pragma unroll
      for (int kt = 0; kt < 4; ++kt) {
        const int k0 = kt * 32 + quad * 8;
        const float* src = (k0 < 64) ? (w_ih1 + arow * 64 + k0)
                                     : (w_hh1 + arow * 64 + (k0 - 64));
        LOADFRAG(src, sA, a2[tt][kt]);
      }
      #pragma unroll
      for (int r = 0; r < 4; ++r) {
        const int crow = r * 64 + 8 * w + 2 * quad + tt;
        const float sC = (r == 2) ? SGP : SS_;
        b1v[tt][r] = sC * (b_ih1[crow] + b_hh1[crow]);
      }
    }
    const int j0 = 8 * w + 2 * quad;
    const int widx = (w >> 2) * 256 + (w & 3) * 64 + n15 * 4 + quad;  // within Zh2 slot
    floatx2 c2v = {0.f, 0.f};

    // E(t): needs all-E past t-1 (h2(t-1) complete) and D past t (h1(t) ready)
    #pragma unroll 4
    for (int t = 0; t < 364; ++t) {
      spin_ge(&cnt[8], 8u * (unsigned)t);
      spin_ge(&cnt[0], 8u * (unsigned)(t + 1));
      const halfx8* r1 = (const halfx8*)(&Zh1[t & 3][0]) + lane;
      const halfx8* r2 = (const halfx8*)(&Zh2[t & 1][0]) + lane;
      const halfx8 bh0 = r1[0], bh1 = r1[64];
      const halfx8 bh2 = r2[0], bh3 = r2[64];
      floatx4 e0 = b1v[0], e1 = b1v[1];
      e0 = MMH(a2[0][0], bh0, e0); e0 = MMH(a2[0][1], bh1, e0);
      e0 = MMH(a2[0][2], bh2, e0); e0 = MMH(a2[0][3], bh3, e0);
      e1 = MMH(a2[1][0], bh0, e1); e1 = MMH(a2[1][1], bh1, e1);
      e1 = MMH(a2[1][2], bh2, e1); e1 = MMH(a2[1][3], bh3, e1);
      unsigned* zw = (unsigned*)(&Zh2[(t + 1) & 1][0]);
      PTAIL(e0, e1, c2v, zw, widx);
      publish(&cnt[8], lane);
    }

    // peel t=364: gates2 -> h2(364) -> out (units j0, j0+1 adjacent)
    {
      spin_ge(&cnt[8], 8u * 364u);
      spin_ge(&cnt[0], 8u * 365u);
      const halfx8* r1 = (const halfx8*)(&Zh1[364 & 3][0]) + lane;
      const halfx8* r2 = (const halfx8*)(&Zh2[364 & 1][0]) + lane;
      const halfx8 bh0 = r1[0], bh1 = r1[64];
      const halfx8 bh2 = r2[0], bh3 = r2[64];
      floatx4 e0 = b1v[0], e1 = b1v[1];
      e0 = MMH(a2[0][0], bh0, e0); e0 = MMH(a2[0][1], bh1, e0);
      e0 = MMH(a2[0][2], bh2, e0); e0 = MMH(a2[0][3], bh3, e0);
      e1 = MMH(a2[1][0], bh0, e1); e1 = MMH(a2[1][1], bh1, e1);
      e1 = MMH(a2[1][2], bh2, e1); e1 = MMH(a2[1][3], bh3, e1);
      PTAIL_CORE(e0, e1, c2v, hv_)
      *(floatx2*)(out + (size_t)(bbase + n15) * 64 + j0) = hv_;
    }
  } else {
    // ================= D group: layer-1 GEMM + combine1 =================
    const int u = wv - 8;
    halfx8 a1[2][2];
    floatx4 wiX[2], wiY[2], wiZ[2], b0v[2];
    #pragma unroll
    for (int tt = 0; tt < 2; ++tt) {
      const int arow = (n15 & 3) * 64 + 8 * u + 2 * (n15 >> 2) + tt;
      #pragma unroll
      for (int kt = 0; kt < 2; ++kt) {
        const float* src = w_hh0 + arow * 64 + kt * 32 + quad * 8;
        LOADFRAG(src, sA, a1[tt][kt]);
      }
      #pragma unroll
      for (int r = 0; r < 4; ++r) {
        const int crow = r * 64 + 8 * u + 2 * quad + tt;
        const float sC = (r == 2) ? SGP : SS_;
        wiX[tt][r] = sC * w_ih0[crow * 3 + 0];
        wiY[tt][r] = sC * w_ih0[crow * 3 + 1];
        wiZ[tt][r] = sC * w_ih0[crow * 3 + 2];
        b0v[tt][r] = sC * (b_ih0[crow] + b_hh0[crow]);
      }
    }
    const int widx = (u >> 2) * 256 + (u & 3) * 64 + n15 * 4 + quad;  // within Zh1 slot
    floatx2 c1v = {0.f, 0.f};

    // prologue: h1(0) from x(0) only -> Zh1[0], then publish (no block barrier)
    {
      const floatx4 xv = *(const floatx4*)(xh + n15 * 4);
      const floatx4 s0 = {xv[0], xv[0], xv[0], xv[0]};
      const floatx4 s1 = {xv[1], xv[1], xv[1], xv[1]};
      const floatx4 s2 = {xv[2], xv[2], xv[2], xv[2]};
      floatx4 d0 = __builtin_elementwise_fma(wiX[0], s0,
                     __builtin_elementwise_fma(wiY[0], s1,
                       __builtin_elementwise_fma(wiZ[0], s2, b0v[0])));
      floatx4 d1 = __builtin_elementwise_fma(wiX[1], s0,
                     __builtin_elementwise_fma(wiY[1], s1,
                       __builtin_elementwise_fma(wiZ[1], s2, b0v[1])));
      PTAIL(d0, d1, c1v, (unsigned*)(&Zh1[0][0]), widx);   // c1v=0 -> f-term vanishes
      publish(&cnt[0], lane);
    }

    // D(t): x-projection hoisted ABOVE the sync (depends only on xh);
    // own-group sync every step; ring-full guard vs E every 2nd step.
    #pragma unroll 4
    for (int t = 1; t < 365; ++t) {
      const floatx4 xv = *(const floatx4*)(xh + t * 64 + n15 * 4);
      const floatx4 s0 = {xv[0], xv[0], xv[0], xv[0]};
      const floatx4 s1 = {xv[1], xv[1], xv[1], xv[1]};
      const floatx4 s2 = {xv[2], xv[2], xv[2], xv[2]};
      floatx4 d0 = __builtin_elementwise_fma(wiX[0], s0,
                     __builtin_elementwise_fma(wiY[0], s1,
                       __builtin_elementwise_fma(wiZ[0], s2, b0v[0])));
      floatx4 d1 = __builtin_elementwise_fma(wiX[1], s0,
                     __builtin_elementwise_fma(wiY[1], s1,
                       __builtin_elementwise_fma(wiZ[1], s2, b0v[1])));
      spin_ge(&cnt[0], 8u * (unsigned)t);
      if (t >= 4 && !(t & 1)) spin_ge(&cnt[8], 8u * (unsigned)(t - 2));
      const halfx8* rp = (const halfx8*)(&Zh1[(t - 1) & 3][0]) + lane;
      const halfx8 bh0 = rp[0], bh1 = rp[64];
      d0 = MMH(a1[0][0], bh0, d0); d0 = MMH(a1[0][1], bh1, d0);
      d1 = MMH(a1[1][0], bh0, d1); d1 = MMH(a1[1][1], bh1, d1);
      unsigned* zw = (unsigned*)(&Zh1[t & 3][0]);
      PTAIL(d0, d1, c1v, zw, widx);
      publish(&cnt[0], lane);
    }
  }
}

extern "C" void kernel_launch(void* const* d_in, const int* in_sizes, int n_in,
                              void* d_out, int out_size, void* d_ws, size_t ws_size,
                              hipStream_t stream) {
  const float* x     = (const float*)d_in[0];
  const float* w_ih0 = (const float*)d_in[1];
  const float* w_hh0 = (const float*)d_in[2];
  const float* b_ih0 = (const float*)d_in[3];
  const float* b_hh0 = (const float*)d_in[4];
  const float* w_ih1 = (const float*)d_in[5];
  const float* w_hh1 = (const float*)d_in[6];
  const float* b_ih1 = (const float*)d_in[7];
  const float* b_hh1 = (const float*)d_in[8];
  float* out = (float*)d_out;

  const int B = in_sizes[0] / (TT * 3);   // 4096
  const int grid = B / NB;                // 256 blocks -> 1 per CU

  lstm2_mfma18<<<dim3(grid), dim3(NTH), 0, stream>>>(
      x, w_ih0, w_hh0, b_ih0, b_hh0, w_ih1, w_hh1, b_ih1, b_hh1, out);
}

// Round 8
// 330.404 us; speedup vs baseline: 1.0444x; 1.0349x over previous
//
#include <hip/hip_runtime.h>

#define TT 365
#define NB 16
#define NTH 1024   // 16 UNIFORM waves: each handles 4 L1 units + 4 L2 units
#define XLEN (NB * TT * 3)

typedef _Float16 halfx8 __attribute__((ext_vector_type(8)));
typedef float floatx4 __attribute__((ext_vector_type(4)));
typedef float floatx2 __attribute__((ext_vector_type(2)));

#define MMH(A, B, C) __builtin_amdgcn_mfma_f32_16x16x32_f16((A), (B), (C), 0, 0, 0)

// Gate rows PRE-SCALED: sigmoid rows by -log2e, g rows by -2log2e.
#define SGP -2.8853900817779268f
#define SGN  2.8853900817779268f
#define SS_  -1.4426950408889634f

static __device__ __forceinline__ float rcpf(float x) { return __builtin_amdgcn_rcpf(x); }
static __device__ __forceinline__ float ex2(float x)  { return __builtin_amdgcn_exp2f(x); }

#define LOADFRAG(SRC, SCALE, HI)                                               \
  do {                                                                         \
    _Pragma("unroll")                                                          \
    for (int jj = 0; jj < 8; ++jj) {                                           \
      (HI)[jj] = (_Float16)((SCALE) * (SRC)[jj]);                              \
    }                                                                          \
  } while (0)

// Packed tail, combined-rcp cell update (1 rcp for f & i*g paths):
//   c' = [c*(1+ei)(1+eg) + SGP*(1-eg)*(1+ef)] / [(1+ef)(1+ei)(1+eg)]
//   h  = (1-ec) / [(1+eo)(1+ec)],  ec = 2^c'  (c kept in SG-scaled domain)
// x-half = this thread's L1 unit, y-half = this thread's L2 unit.
#define PTAIL_CORE(PA, PB, CS2, HOUT)                                          \
  const floatx2 one_ = {1.0f, 1.0f};                                           \
  const floatx2 ei_ = {ex2((PA)[0]), ex2((PB)[0])};                            \
  const floatx2 ef_ = {ex2((PA)[1]), ex2((PB)[1])};                            \
  const floatx2 eg_ = {ex2((PA)[2]), ex2((PB)[2])};                            \
  const floatx2 eo_ = {ex2((PA)[3]), ex2((PB)[3])};                            \
  const floatx2 sgn2_ = {SGN, SGN};                                            \
  const floatx2 sgp2_ = {SGP, SGP};                                            \
  const floatx2 fd_ = one_ + ef_;                                              \
  const floatx2 P1_ = (one_ + ei_) * (one_ + eg_);                             \
  const floatx2 Dp_ = P1_ * fd_;                                               \
  const floatx2 R_  = {rcpf(Dp_.x), rcpf(Dp_.y)};                              \
  const floatx2 T_  = (sgn2_ * eg_ + sgp2_) * fd_;                             \
  (CS2) = ((CS2) * P1_ + T_) * R_;                                             \
  (CS2).x = fminf((CS2).x, 60.0f);                                             \
  (CS2).y = fminf((CS2).y, 60.0f);                                             \
  const floatx2 ec_ = {ex2((CS2).x), ex2((CS2).y)};                            \
  const floatx2 P2_ = (one_ + eo_) * (one_ + ec_);                             \
  const floatx2 R2_ = {rcpf(P2_.x), rcpf(P2_.y)};                              \
  const floatx2 HOUT = (one_ - ec_) * R2_;

__global__ __launch_bounds__(NTH)
__attribute__((amdgpu_waves_per_eu(4, 4)))
void lstm2_mfma19(
    const float* __restrict__ x,
    const float* __restrict__ w_ih0, const float* __restrict__ w_hh0,
    const float* __restrict__ b_ih0, const float* __restrict__ b_hh0,
    const float* __restrict__ w_ih1, const float* __restrict__ w_hh1,
    const float* __restrict__ b_ih1, const float* __restrict__ b_hh1,
    float* __restrict__ out)
{
  // Z[buf]: 2048 shorts = [kt 0..3][lane][8]; kt0,1 = h1 (k 0..63), kt2,3 = h2
  __shared__ __align__(16) unsigned short Z[2][2048];
  __shared__ __align__(16) float xh[TT * 16 * 4];   // x re-laid: [t][b][4]

  const int tid  = threadIdx.x;
  const int lane = tid & 63;
  const int wv   = tid >> 6;
  const int n15  = lane & 15;
  const int quad = lane >> 4;
  const int wu   = wv & 7;     // unit-group
  const int ttw  = wv >> 3;    // which half of the old tt-pair this wave owns
  const int bbase = blockIdx.x * NB;
  const float sA = ((n15 & 3) == 2) ? SGP : SS_;

  // stage x -> [t][b][4] layout (coalesced global reads, scattered LDS writes)
  {
    const float* xg = x + (size_t)bbase * (TT * 3);
    for (int i = tid; i < XLEN; i += NTH) {
      const int b = i / 1095;
      const int rem = i - b * 1095;
      const int t = rem / 3;
      const int c = rem - 3 * t;
      xh[(t * 16 + b) * 4 + c] = xg[i];
    }
    for (int i = tid; i < 2048; i += NTH) { Z[0][i] = 0; Z[1][i] = 0; }
  }
  __syncthreads();   // barrier #1

  // -------- per-wave fragments: BOTH layers --------
  halfx8 a1[2], a2[4];
  floatx4 wiX, wiY, wiZ, b0v, b1v;
  {
    const int arow = (n15 & 3) * 64 + 8 * wu + 2 * (n15 >> 2) + ttw;
    #pragma unroll
    for (int kt = 0; kt < 4; ++kt) {
      const int k0 = kt * 32 + quad * 8;
      const float* src = (k0 < 64) ? (w_ih1 + arow * 64 + k0)
                                   : (w_hh1 + arow * 64 + (k0 - 64));
      LOADFRAG(src, sA, a2[kt]);
    }
    #pragma unroll
    for (int kt = 0; kt < 2; ++kt) {
      const float* src = w_hh0 + arow * 64 + kt * 32 + quad * 8;
      LOADFRAG(src, sA, a1[kt]);
    }
  }
  const int u = 8 * wu + 2 * quad + ttw;   // this thread's unit (both layers)
  #pragma unroll
  for (int r = 0; r < 4; ++r) {
    const int crow = r * 64 + u;
    const float sC = (r == 2) ? SGP : SS_;
    wiX[r] = sC * w_ih0[crow * 3 + 0];
    wiY[r] = sC * w_ih0[crow * 3 + 1];
    wiZ[r] = sC * w_ih0[crow * 3 + 2];
    b0v[r] = sC * (b_ih0[crow] + b_hh0[crow]);
    b1v[r] = sC * (b_ih1[crow] + b_hh1[crow]);
  }
  // LDS short index of h[k][batch]: (k>>5)*512 + (((k>>3)&3)*16 + b)*8 + (k&7)
  const int widx1 = (u >> 5) * 512 + (((u >> 3) & 3) * 16 + n15) * 8 + (u & 7);
  const int widx2 = widx1 + 1024;         // h2 region (kt 2,3)
  floatx2 cs = {0.f, 0.f};                // packed cell state {c1, c2}

  unsigned short* const Zs0 = &Z[0][0];
  unsigned short* const Zs1 = &Z[1][0];
  const halfx8* const Z0r = (const halfx8*)Zs0 + lane;
  const halfx8* const Z1r = (const halfx8*)Zs1 + lane;

  // prologue: h1(0) from x(0) only -> Z0 h1 region (h2 half discarded, c2 reset)
  {
    const floatx4 xv = *(const floatx4*)(xh + n15 * 4);
    const floatx4 s0 = {xv[0], xv[0], xv[0], xv[0]};
    const floatx4 s1 = {xv[1], xv[1], xv[1], xv[1]};
    const floatx4 s2 = {xv[2], xv[2], xv[2], xv[2]};
    floatx4 d0 = __builtin_elementwise_fma(wiX, s0,
                   __builtin_elementwise_fma(wiY, s1,
                     __builtin_elementwise_fma(wiZ, s2, b0v)));
    PTAIL_CORE(d0, d0, cs, hv_)
    const unsigned pk =
        __builtin_bit_cast(unsigned, __builtin_amdgcn_cvt_pkrtz(hv_.x, hv_.x));
    Zs0[widx1] = (unsigned short)pk;
    cs.y = 0.f;   // c2 starts clean
  }
  __syncthreads();   // barrier #2

  // phase p: D computes h1(p+1) [x(p+1) + h1(p)], E computes h2(p) [h1(p)+h2(p-1)]
#define STEP(ZRP, ZW, XT)                                                      \
  do {                                                                         \
    const halfx8 bh0 = (ZRP)[0],   bh1 = (ZRP)[64];                            \
    const halfx8 bh2 = (ZRP)[128], bh3 = (ZRP)[192];                           \
    const floatx4 xv = *(const floatx4*)(xh + (XT) * 64 + n15 * 4);            \
    const floatx4 s0 = {xv[0], xv[0], xv[0], xv[0]};                           \
    const floatx4 s1 = {xv[1], xv[1], xv[1], xv[1]};                           \
    const floatx4 s2 = {xv[2], xv[2], xv[2], xv[2]};                           \
    floatx4 d0 = __builtin_elementwise_fma(wiX, s0,                            \
                   __builtin_elementwise_fma(wiY, s1,                          \
                     __builtin_elementwise_fma(wiZ, s2, b0v)));                \
    floatx4 e0 = b1v;                                                          \
    e0 = MMH(a2[0], bh0, e0); e0 = MMH(a2[1], bh1, e0);                        \
    e0 = MMH(a2[2], bh2, e0); e0 = MMH(a2[3], bh3, e0);                        \
    d0 = MMH(a1[0], bh0, d0); d0 = MMH(a1[1], bh1, d0);                        \
    PTAIL_CORE(d0, e0, cs, hv_)                                                \
    const unsigned pk =                                                        \
        __builtin_bit_cast(unsigned, __builtin_amdgcn_cvt_pkrtz(hv_.x, hv_.y)); \
    (ZW)[widx1] = (unsigned short)pk;                                          \
    (ZW)[widx2] = (unsigned short)(pk >> 16);                                  \
    __syncthreads();                                                           \
  } while (0)

  for (int p = 0; p < 364; p += 2) {
    STEP(Z0r, Zs1, p + 1);
    STEP(Z1r, Zs0, p + 2);
  }

  // peel: h2(364) from buf0 (h1(364), h2(363)) -> out
  {
    const halfx8 bh0 = Z0r[0],   bh1 = Z0r[64];
    const halfx8 bh2 = Z0r[128], bh3 = Z0r[192];
    floatx4 e0 = b1v;
    e0 = MMH(a2[0], bh0, e0); e0 = MMH(a2[1], bh1, e0);
    e0 = MMH(a2[2], bh2, e0); e0 = MMH(a2[3], bh3, e0);
    PTAIL_CORE(e0, e0, cs, hv_)
    out[(size_t)(bbase + n15) * 64 + u] = hv_.y;
  }
}

extern "C" void kernel_launch(void* const* d_in, const int* in_sizes, int n_in,
                              void* d_out, int out_size, void* d_ws, size_t ws_size,
                              hipStream_t stream) {
  const float* x     = (const float*)d_in[0];
  const float* w_ih0 = (const float*)d_in[1];
  const float* w_hh0 = (const float*)d_in[2];
  const float* b_ih0 = (const float*)d_in[3];
  const float* b_hh0 = (const float*)d_in[4];
  const float* w_ih1 = (const float*)d_in[5];
  const float* w_hh1 = (const float*)d_in[6];
  const float* b_ih1 = (const float*)d_in[7];
  const float* b_hh1 = (const float*)d_in[8];
  float* out = (float*)d_out;

  const int B = in_sizes[0] / (TT * 3);   // 4096
  const int grid = B / NB;                // 256 blocks -> 1 per CU

  lstm2_mfma19<<<dim3(grid), dim3(NTH), 0, stream>>>(
      x, w_ih0, w_hh0, b_ih0, b_hh0, w_ih1, w_hh1, b_ih1, b_hh1, out);
}